// Round 1
// baseline (1126.607 us; speedup 1.0000x reference)
//
#include <hip/hip_runtime.h>
#include <hip/hip_bf16.h>

#define N_OBJ 8192
#define N_REL 32768
#define HID   512
#define POOL  4096
#define NOC   151
#define NRC   51

typedef __bf16 bf16_t;
typedef __attribute__((ext_vector_type(8))) __bf16 bf16x8;
typedef __attribute__((ext_vector_type(4))) __bf16 bf16x4;
typedef __attribute__((ext_vector_type(4))) float f32x4;

// Async global->LDS, 16B per lane. LDS dest semantics: wave-uniform base + lane*16.
__device__ __forceinline__ void async_copy16(const void* g, void* l) {
    __builtin_amdgcn_global_load_lds((__attribute__((address_space(1))) void*)g,
                                     (__attribute__((address_space(3))) void*)l,
                                     16, 0, 0);
}

// ---------------- small prep kernels ----------------

__global__ void convert_bf16_kernel(const float* __restrict__ in,
                                    bf16_t* __restrict__ out, int n4) {
    int i = blockIdx.x * blockDim.x + threadIdx.x;
    int stride = gridDim.x * blockDim.x;
    for (; i < n4; i += stride) {
        float4 v = ((const float4*)in)[i];
        bf16x4 o;
        o[0] = (bf16_t)v.x; o[1] = (bf16_t)v.y; o[2] = (bf16_t)v.z; o[3] = (bf16_t)v.w;
        ((bf16x4*)out)[i] = o;
    }
}

// in: f32 [K][C] row-major -> out: bf16 [Cpad][K] (transposed, zero-padded in C)
__global__ void transpose_bf16_kernel(const float* __restrict__ in,
                                      bf16_t* __restrict__ out,
                                      int K, int C, int Cpad) {
    __shared__ float tile[32][33];
    int cb = blockIdx.x * 32, kb = blockIdx.y * 32;
    int tx = threadIdx.x, ty = threadIdx.y; // 32 x 8
    #pragma unroll
    for (int i = 0; i < 32; i += 8) {
        int k = kb + ty + i, c = cb + tx;
        float v = (k < K && c < C) ? in[(size_t)k * C + c] : 0.0f;
        tile[ty + i][tx] = v;
    }
    __syncthreads();
    #pragma unroll
    for (int i = 0; i < 32; i += 8) {
        int c = cb + ty + i, k = kb + tx;
        if (c < Cpad && k < K) out[(size_t)c * K + k] = (bf16_t)tile[tx][ty + i];
    }
}

__global__ void pair_kernel(const int* __restrict__ rel, const int* __restrict__ obj,
                            int* __restrict__ pid) {
    int r = blockIdx.x * blockDim.x + threadIdx.x;
    if (r < N_REL) pid[r] = obj[rel[2 * r]] * NOC + obj[rel[2 * r + 1]];
}

// ---------------- GEMM1: C1 = relu(ec @ Wemb + b), bf16 out [8192][1024] ----------------
// 128x128 tile, BK=64, 4 waves (2x2), 16x16x32 bf16 MFMA.

__global__ __launch_bounds__(256, 2) void gemm1_kernel(
    const bf16_t* __restrict__ A,    // [8192][512]
    const bf16_t* __restrict__ Bt,   // [1024][512]  (W_post_emb transposed)
    const float* __restrict__ bias,  // [1024]
    bf16_t* __restrict__ C)          // [8192][1024]
{
    __shared__ __align__(16) bf16_t As[128 * 64];
    __shared__ __align__(16) bf16_t Bs[128 * 64];
    const int tid = threadIdx.x;
    const int w = tid >> 6, lane = tid & 63;
    const int m0 = blockIdx.x * 128, n0 = blockIdx.y * 128;
    const int lrow = tid >> 3, lcs = tid & 7;
    const int wm = w & 1, wn = w >> 1;
    const int quad = lane >> 4, l16 = lane & 15;
    f32x4 acc[4][4] = {};

    for (int kt = 0; kt < HID / 64; ++kt) {
        const int k0 = kt * 64;
        #pragma unroll
        for (int j = 0; j < 4; ++j) {
            int ml = j * 32 + lrow;
            int cg = lcs ^ (ml & 7);
            async_copy16(A + (size_t)(m0 + ml) * HID + k0 + cg * 8, &As[ml * 64 + lcs * 8]);
        }
        #pragma unroll
        for (int j = 0; j < 4; ++j) {
            int nl = j * 32 + lrow;
            int cg = lcs ^ (nl & 7);
            async_copy16(Bt + (size_t)(n0 + nl) * HID + k0 + cg * 8, &Bs[nl * 64 + lcs * 8]);
        }
        __syncthreads();
        #pragma unroll
        for (int kb = 0; kb < 2; ++kb) {
            bf16x8 a[4], b[4];
            #pragma unroll
            for (int i = 0; i < 4; ++i) {
                int m = wm * 64 + i * 16 + l16;
                int ch = (kb * 4 + quad) ^ (m & 7);
                a[i] = *(const bf16x8*)&As[m * 64 + ch * 8];
            }
            #pragma unroll
            for (int i = 0; i < 4; ++i) {
                int n = wn * 64 + i * 16 + l16;
                int ch = (kb * 4 + quad) ^ (n & 7);
                b[i] = *(const bf16x8*)&Bs[n * 64 + ch * 8];
            }
            #pragma unroll
            for (int i = 0; i < 4; ++i)
                #pragma unroll
                for (int jj = 0; jj < 4; ++jj)
                    acc[i][jj] = __builtin_amdgcn_mfma_f32_16x16x32_bf16(a[i], b[jj], acc[i][jj], 0, 0, 0);
        }
        __syncthreads();
    }
    #pragma unroll
    for (int i = 0; i < 4; ++i) {
        int rbase = m0 + wm * 64 + i * 16 + quad * 4;
        #pragma unroll
        for (int jj = 0; jj < 4; ++jj) {
            int c = n0 + wn * 64 + jj * 16 + l16;
            float bv = bias[c];
            #pragma unroll
            for (int rr = 0; rr < 4; ++rr) {
                float v = acc[i][jj][rr] + bv;
                v = fmaxf(v, 0.0f);
                C[(size_t)(rbase + rr) * 1024 + c] = (bf16_t)v;
            }
        }
    }
}

// ---------------- GEMM2: scaled = (gather(C1) @ Wcat + b) * union, bf16 out ----------------

__global__ __launch_bounds__(256, 2) void gemm2_kernel(
    const bf16_t* __restrict__ C1,    // [8192][1024]
    const bf16_t* __restrict__ Bt,    // [4096][1024] (W_post_cat transposed)
    const int* __restrict__ rel,      // [32768][2]
    const float* __restrict__ bias,   // [4096]
    const float* __restrict__ uni,    // [32768][4096]
    bf16_t* __restrict__ scaled)      // [32768][4096]
{
    __shared__ __align__(16) bf16_t As[128 * 64];
    __shared__ __align__(16) bf16_t Bs[128 * 64];
    const int tid = threadIdx.x;
    const int w = tid >> 6, lane = tid & 63;
    const int m0 = blockIdx.x * 128, n0 = blockIdx.y * 128;
    const int lrow = tid >> 3, lcs = tid & 7;
    const int wm = w & 1, wn = w >> 1;
    const int quad = lane >> 4, l16 = lane & 15;
    f32x4 acc[4][4] = {};

    // prefetch gather indices for the 4 rows this thread stages
    int i0[4], i1[4];
    #pragma unroll
    for (int j = 0; j < 4; ++j) {
        int r = m0 + j * 32 + lrow;
        i0[j] = rel[2 * r];
        i1[j] = rel[2 * r + 1];
    }

    for (int kt = 0; kt < 1024 / 64; ++kt) {
        const int k0 = kt * 64;
        const bool tail = (k0 >= 512);
        #pragma unroll
        for (int j = 0; j < 4; ++j) {
            int ml = j * 32 + lrow;
            int ridx = tail ? i1[j] : i0[j];
            int cg = lcs ^ (ml & 7);
            async_copy16(C1 + (size_t)ridx * 1024 + k0 + cg * 8, &As[ml * 64 + lcs * 8]);
        }
        #pragma unroll
        for (int j = 0; j < 4; ++j) {
            int nl = j * 32 + lrow;
            int cg = lcs ^ (nl & 7);
            async_copy16(Bt + (size_t)(n0 + nl) * 1024 + k0 + cg * 8, &Bs[nl * 64 + lcs * 8]);
        }
        __syncthreads();
        #pragma unroll
        for (int kb = 0; kb < 2; ++kb) {
            bf16x8 a[4], b[4];
            #pragma unroll
            for (int i = 0; i < 4; ++i) {
                int m = wm * 64 + i * 16 + l16;
                int ch = (kb * 4 + quad) ^ (m & 7);
                a[i] = *(const bf16x8*)&As[m * 64 + ch * 8];
            }
            #pragma unroll
            for (int i = 0; i < 4; ++i) {
                int n = wn * 64 + i * 16 + l16;
                int ch = (kb * 4 + quad) ^ (n & 7);
                b[i] = *(const bf16x8*)&Bs[n * 64 + ch * 8];
            }
            #pragma unroll
            for (int i = 0; i < 4; ++i)
                #pragma unroll
                for (int jj = 0; jj < 4; ++jj)
                    acc[i][jj] = __builtin_amdgcn_mfma_f32_16x16x32_bf16(a[i], b[jj], acc[i][jj], 0, 0, 0);
        }
        __syncthreads();
    }
    #pragma unroll
    for (int i = 0; i < 4; ++i) {
        int rbase = m0 + wm * 64 + i * 16 + quad * 4;
        #pragma unroll
        for (int jj = 0; jj < 4; ++jj) {
            int c = n0 + wn * 64 + jj * 16 + l16;
            float bv = bias[c];
            #pragma unroll
            for (int rr = 0; rr < 4; ++rr) {
                size_t idx = (size_t)(rbase + rr) * POOL + c;
                float v = (acc[i][jj][rr] + bv) * uni[idx];
                scaled[idx] = (bf16_t)v;
            }
        }
    }
}

// ---------------- GEMM3: out = scaled @ Wctx + b_ctx + freq[pid]  (N=51 pad 64) ----------------
// 128(M) x 64(N) tile, waves 2x2 -> each wave 64x32.

__global__ __launch_bounds__(256, 2) void gemm3_kernel(
    const bf16_t* __restrict__ A,     // scaled [32768][4096]
    const bf16_t* __restrict__ Bt,    // Wctx_t [64][4096]
    const float* __restrict__ b_ctx,  // [51]
    const float* __restrict__ freq,   // [151*151][51]
    const int* __restrict__ pid,      // [32768]
    float* __restrict__ out)          // [32768][51]
{
    __shared__ __align__(16) bf16_t As[128 * 64];
    __shared__ __align__(16) bf16_t Bs[64 * 64];
    const int tid = threadIdx.x;
    const int w = tid >> 6, lane = tid & 63;
    const int m0 = blockIdx.x * 128;
    const int lrow = tid >> 3, lcs = tid & 7;
    const int wm = w & 1, wn = w >> 1;
    const int quad = lane >> 4, l16 = lane & 15;
    f32x4 acc[4][2] = {};

    for (int kt = 0; kt < POOL / 64; ++kt) {
        const int k0 = kt * 64;
        #pragma unroll
        for (int j = 0; j < 4; ++j) {
            int ml = j * 32 + lrow;
            int cg = lcs ^ (ml & 7);
            async_copy16(A + (size_t)(m0 + ml) * POOL + k0 + cg * 8, &As[ml * 64 + lcs * 8]);
        }
        #pragma unroll
        for (int j = 0; j < 2; ++j) {
            int nl = j * 32 + lrow;
            int cg = lcs ^ (nl & 7);
            async_copy16(Bt + (size_t)nl * POOL + k0 + cg * 8, &Bs[nl * 64 + lcs * 8]);
        }
        __syncthreads();
        #pragma unroll
        for (int kb = 0; kb < 2; ++kb) {
            bf16x8 a[4], b[2];
            #pragma unroll
            for (int i = 0; i < 4; ++i) {
                int m = wm * 64 + i * 16 + l16;
                int ch = (kb * 4 + quad) ^ (m & 7);
                a[i] = *(const bf16x8*)&As[m * 64 + ch * 8];
            }
            #pragma unroll
            for (int i = 0; i < 2; ++i) {
                int n = wn * 32 + i * 16 + l16;
                int ch = (kb * 4 + quad) ^ (n & 7);
                b[i] = *(const bf16x8*)&Bs[n * 64 + ch * 8];
            }
            #pragma unroll
            for (int i = 0; i < 4; ++i)
                #pragma unroll
                for (int jj = 0; jj < 2; ++jj)
                    acc[i][jj] = __builtin_amdgcn_mfma_f32_16x16x32_bf16(a[i], b[jj], acc[i][jj], 0, 0, 0);
        }
        __syncthreads();
    }
    #pragma unroll
    for (int i = 0; i < 4; ++i) {
        int rbase = m0 + wm * 64 + i * 16 + quad * 4;
        #pragma unroll
        for (int jj = 0; jj < 2; ++jj) {
            int c = wn * 32 + jj * 16 + l16;
            if (c < NRC) {
                float bv = b_ctx[c];
                #pragma unroll
                for (int rr = 0; rr < 4; ++rr) {
                    int r = rbase + rr;
                    out[(size_t)r * NRC + c] = acc[i][jj][rr] + bv + freq[(size_t)pid[r] * NRC + c];
                }
            }
        }
    }
}

// ---------------- launcher ----------------

extern "C" void kernel_launch(void* const* d_in, const int* in_sizes, int n_in,
                              void* d_out, int out_size, void* d_ws, size_t ws_size,
                              hipStream_t stream) {
    const float* edge_ctx = (const float*)d_in[0];
    const float* uni      = (const float*)d_in[1];
    const int*   rel      = (const int*)d_in[2];
    const int*   obj      = (const int*)d_in[3];
    const float* W_emb    = (const float*)d_in[4];
    const float* b_emb    = (const float*)d_in[5];
    const float* W_cat    = (const float*)d_in[6];
    const float* b_cat    = (const float*)d_in[7];
    const float* W_ctx    = (const float*)d_in[8];
    const float* b_ctx    = (const float*)d_in[9];
    const float* freq     = (const float*)d_in[10];
    float* out = (float*)d_out;

    char* p = (char*)d_ws;
    bf16_t* C1     = (bf16_t*)p; p += (size_t)N_OBJ * 1024 * 2;
    bf16_t* ecb    = (bf16_t*)p; p += (size_t)N_OBJ * HID * 2;
    bf16_t* Wemb_t = (bf16_t*)p; p += (size_t)1024 * HID * 2;
    bf16_t* Wcat_t = (bf16_t*)p; p += (size_t)POOL * 1024 * 2;
    bf16_t* Wctx_t = (bf16_t*)p; p += (size_t)64 * POOL * 2;
    int*    pid    = (int*)p;    p += (size_t)N_REL * 4;
    bf16_t* scaled = (bf16_t*)p; p += (size_t)N_REL * POOL * 2;

    convert_bf16_kernel<<<2048, 256, 0, stream>>>(edge_ctx, ecb, N_OBJ * HID / 4);
    transpose_bf16_kernel<<<dim3(1024 / 32, HID / 32), dim3(32, 8), 0, stream>>>(W_emb, Wemb_t, HID, 1024, 1024);
    transpose_bf16_kernel<<<dim3(POOL / 32, 1024 / 32), dim3(32, 8), 0, stream>>>(W_cat, Wcat_t, 1024, POOL, POOL);
    transpose_bf16_kernel<<<dim3(2, POOL / 32), dim3(32, 8), 0, stream>>>(W_ctx, Wctx_t, POOL, NRC, 64);
    pair_kernel<<<N_REL / 256, 256, 0, stream>>>(rel, obj, pid);

    gemm1_kernel<<<dim3(N_OBJ / 128, 1024 / 128), 256, 0, stream>>>(ecb, Wemb_t, b_emb, C1);
    gemm2_kernel<<<dim3(N_REL / 128, POOL / 128), 256, 0, stream>>>(C1, Wcat_t, rel, b_cat, uni, scaled);
    gemm3_kernel<<<dim3(N_REL / 128, 1), 256, 0, stream>>>(scaled, Wctx_t, b_ctx, freq, pid, out);
}

// Round 2
// 1102.866 us; speedup vs baseline: 1.0215x; 1.0215x over previous
//
#include <hip/hip_runtime.h>
#include <hip/hip_bf16.h>

#define N_OBJ 8192
#define N_REL 32768
#define HID   512
#define POOL  4096
#define NOC   151
#define NRC   51

typedef __bf16 bf16_t;
typedef __attribute__((ext_vector_type(8))) __bf16 bf16x8;
typedef __attribute__((ext_vector_type(4))) __bf16 bf16x4;
typedef __attribute__((ext_vector_type(4))) float f32x4;

// Async global->LDS, 16B per lane. LDS dest semantics: wave-uniform base + lane*16.
__device__ __forceinline__ void async_copy16(const void* g, void* l) {
    __builtin_amdgcn_global_load_lds((__attribute__((address_space(1))) void*)g,
                                     (__attribute__((address_space(3))) void*)l,
                                     16, 0, 0);
}

// ---------------- small prep kernels ----------------

__global__ void convert_bf16_kernel(const float* __restrict__ in,
                                    bf16_t* __restrict__ out, int n4) {
    int i = blockIdx.x * blockDim.x + threadIdx.x;
    int stride = gridDim.x * blockDim.x;
    for (; i < n4; i += stride) {
        float4 v = ((const float4*)in)[i];
        bf16x4 o;
        o[0] = (bf16_t)v.x; o[1] = (bf16_t)v.y; o[2] = (bf16_t)v.z; o[3] = (bf16_t)v.w;
        ((bf16x4*)out)[i] = o;
    }
}

// in: f32 [K][C] row-major -> out: bf16 [Cpad][K] (transposed, zero-padded in C)
__global__ void transpose_bf16_kernel(const float* __restrict__ in,
                                      bf16_t* __restrict__ out,
                                      int K, int C, int Cpad) {
    __shared__ float tile[32][33];
    int cb = blockIdx.x * 32, kb = blockIdx.y * 32;
    int tx = threadIdx.x, ty = threadIdx.y; // 32 x 8
    #pragma unroll
    for (int i = 0; i < 32; i += 8) {
        int k = kb + ty + i, c = cb + tx;
        float v = (k < K && c < C) ? in[(size_t)k * C + c] : 0.0f;
        tile[ty + i][tx] = v;
    }
    __syncthreads();
    #pragma unroll
    for (int i = 0; i < 32; i += 8) {
        int c = cb + ty + i, k = kb + tx;
        if (c < Cpad && k < K) out[(size_t)c * K + k] = (bf16_t)tile[tx][ty + i];
    }
}

// out[r][c] = b_ctx[c] + freq[pid(r)][c]  (pre-fill for the fused atomics)
__global__ void init_out_kernel(const int* __restrict__ rel, const int* __restrict__ obj,
                                const float* __restrict__ b_ctx,
                                const float* __restrict__ freq,
                                float* __restrict__ out) {
    int r = blockIdx.x * 4 + (threadIdx.x >> 6);
    int c = threadIdx.x & 63;
    if (c < NRC) {
        int pid = obj[rel[2 * r]] * NOC + obj[rel[2 * r + 1]];
        out[(size_t)r * NRC + c] = b_ctx[c] + freq[(size_t)pid * NRC + c];
    }
}

// ---------------- GEMM1: C1 = relu(ec @ Wemb + b), bf16 out [8192][1024] ----------------
// 128x128 tile, BK=64, 4 waves (2x2), 16x16x32 bf16 MFMA.

__global__ __launch_bounds__(256, 2) void gemm1_kernel(
    const bf16_t* __restrict__ A,    // [8192][512]
    const bf16_t* __restrict__ Bt,   // [1024][512]  (W_post_emb transposed)
    const float* __restrict__ bias,  // [1024]
    bf16_t* __restrict__ C)          // [8192][1024]
{
    __shared__ __align__(16) bf16_t As[128 * 64];
    __shared__ __align__(16) bf16_t Bs[128 * 64];
    const int tid = threadIdx.x;
    const int w = tid >> 6, lane = tid & 63;
    const int m0 = blockIdx.x * 128, n0 = blockIdx.y * 128;
    const int lrow = tid >> 3, lcs = tid & 7;
    const int wm = w & 1, wn = w >> 1;
    const int quad = lane >> 4, l16 = lane & 15;
    f32x4 acc[4][4] = {};

    for (int kt = 0; kt < HID / 64; ++kt) {
        const int k0 = kt * 64;
        #pragma unroll
        for (int j = 0; j < 4; ++j) {
            int ml = j * 32 + lrow;
            int cg = lcs ^ (ml & 7);
            async_copy16(A + (size_t)(m0 + ml) * HID + k0 + cg * 8, &As[ml * 64 + lcs * 8]);
        }
        #pragma unroll
        for (int j = 0; j < 4; ++j) {
            int nl = j * 32 + lrow;
            int cg = lcs ^ (nl & 7);
            async_copy16(Bt + (size_t)(n0 + nl) * HID + k0 + cg * 8, &Bs[nl * 64 + lcs * 8]);
        }
        __syncthreads();
        #pragma unroll
        for (int kb = 0; kb < 2; ++kb) {
            bf16x8 a[4], b[4];
            #pragma unroll
            for (int i = 0; i < 4; ++i) {
                int m = wm * 64 + i * 16 + l16;
                int ch = (kb * 4 + quad) ^ (m & 7);
                a[i] = *(const bf16x8*)&As[m * 64 + ch * 8];
            }
            #pragma unroll
            for (int i = 0; i < 4; ++i) {
                int n = wn * 64 + i * 16 + l16;
                int ch = (kb * 4 + quad) ^ (n & 7);
                b[i] = *(const bf16x8*)&Bs[n * 64 + ch * 8];
            }
            #pragma unroll
            for (int i = 0; i < 4; ++i)
                #pragma unroll
                for (int jj = 0; jj < 4; ++jj)
                    acc[i][jj] = __builtin_amdgcn_mfma_f32_16x16x32_bf16(a[i], b[jj], acc[i][jj], 0, 0, 0);
        }
        __syncthreads();
    }
    #pragma unroll
    for (int i = 0; i < 4; ++i) {
        int rbase = m0 + wm * 64 + i * 16 + quad * 4;
        #pragma unroll
        for (int jj = 0; jj < 4; ++jj) {
            int c = n0 + wn * 64 + jj * 16 + l16;
            float bv = bias[c];
            #pragma unroll
            for (int rr = 0; rr < 4; ++rr) {
                float v = acc[i][jj][rr] + bv;
                v = fmaxf(v, 0.0f);
                C[(size_t)(rbase + rr) * 1024 + c] = (bf16_t)v;
            }
        }
    }
}

// ---------------- GEMM2 fused: scaled-tile -> LDS -> x Wctx -> atomicAdd out ----------------

__global__ __launch_bounds__(256, 2) void gemm2_fused_kernel(
    const bf16_t* __restrict__ C1,     // [8192][1024]
    const bf16_t* __restrict__ Bt,     // [4096][1024] (W_post_cat transposed)
    const bf16_t* __restrict__ Wctx_t, // [64][4096]   (W_ctx transposed, rows 51..63 zero)
    const int* __restrict__ rel,       // [32768][2]
    const float* __restrict__ bias,    // [4096] (b_cat)
    const float* __restrict__ uni,     // [32768][4096]
    float* __restrict__ out)           // [32768][51], pre-filled with b_ctx + freq
{
    // 32 KB LDS: As/Bs during the K-loop, reused as the scaled tile Ss afterwards.
    __shared__ __align__(16) bf16_t smem[128 * 64 * 2];
    bf16_t* As = smem;
    bf16_t* Bs = smem + 128 * 64;
    bf16_t* Ss = smem;                 // [128][128] bf16, XOR-swizzled 16B chunks

    const int tid = threadIdx.x;
    const int w = tid >> 6, lane = tid & 63;
    const int m0 = blockIdx.x * 128, n0 = blockIdx.y * 128;
    const int lrow = tid >> 3, lcs = tid & 7;
    const int wm = w & 1, wn = w >> 1;
    const int quad = lane >> 4, l16 = lane & 15;
    f32x4 acc[4][4] = {};

    int i0[4], i1[4];
    #pragma unroll
    for (int j = 0; j < 4; ++j) {
        int r = m0 + j * 32 + lrow;
        i0[j] = rel[2 * r];
        i1[j] = rel[2 * r + 1];
    }

    for (int kt = 0; kt < 1024 / 64; ++kt) {
        const int k0 = kt * 64;
        const bool tail = (k0 >= 512);
        #pragma unroll
        for (int j = 0; j < 4; ++j) {
            int ml = j * 32 + lrow;
            int ridx = tail ? i1[j] : i0[j];
            int cg = lcs ^ (ml & 7);
            async_copy16(C1 + (size_t)ridx * 1024 + k0 + cg * 8, &As[ml * 64 + lcs * 8]);
        }
        #pragma unroll
        for (int j = 0; j < 4; ++j) {
            int nl = j * 32 + lrow;
            int cg = lcs ^ (nl & 7);
            async_copy16(Bt + (size_t)(n0 + nl) * 1024 + k0 + cg * 8, &Bs[nl * 64 + lcs * 8]);
        }
        __syncthreads();
        #pragma unroll
        for (int kb = 0; kb < 2; ++kb) {
            bf16x8 a[4], b[4];
            #pragma unroll
            for (int i = 0; i < 4; ++i) {
                int m = wm * 64 + i * 16 + l16;
                int ch = (kb * 4 + quad) ^ (m & 7);
                a[i] = *(const bf16x8*)&As[m * 64 + ch * 8];
            }
            #pragma unroll
            for (int i = 0; i < 4; ++i) {
                int n = wn * 64 + i * 16 + l16;
                int ch = (kb * 4 + quad) ^ (n & 7);
                b[i] = *(const bf16x8*)&Bs[n * 64 + ch * 8];
            }
            #pragma unroll
            for (int i = 0; i < 4; ++i)
                #pragma unroll
                for (int jj = 0; jj < 4; ++jj)
                    acc[i][jj] = __builtin_amdgcn_mfma_f32_16x16x32_bf16(a[i], b[jj], acc[i][jj], 0, 0, 0);
        }
        __syncthreads();
    }

    // Epilogue A: scaled = (acc + b_cat) * uni -> bf16 -> Ss (swizzled row-major [128][128])
    #pragma unroll
    for (int i = 0; i < 4; ++i) {
        int lm_base = wm * 64 + i * 16 + quad * 4;   // local row
        #pragma unroll
        for (int jj = 0; jj < 4; ++jj) {
            int col = wn * 64 + jj * 16 + l16;       // local col (the n-dim)
            float bv = bias[n0 + col];
            #pragma unroll
            for (int rr = 0; rr < 4; ++rr) {
                int lm = lm_base + rr;
                float v = (acc[i][jj][rr] + bv) * uni[(size_t)(m0 + lm) * POOL + n0 + col];
                int ch = (col >> 3) ^ (lm & 15);
                Ss[lm * 128 + ch * 8 + (col & 7)] = (bf16_t)v;
            }
        }
    }
    __syncthreads();

    // Epilogue B: partial[128][64] = Ss(128x128) @ Wctx[n0:n0+128][0:64]; atomicAdd into out.
    f32x4 acc2[4][2] = {};
    #pragma unroll
    for (int kb = 0; kb < 4; ++kb) {   // K = 128, steps of 32
        bf16x8 a2[4], b2[2];
        #pragma unroll
        for (int i = 0; i < 4; ++i) {
            int m = wm * 64 + i * 16 + l16;
            int ch = (kb * 4 + quad) ^ (m & 15);
            a2[i] = *(const bf16x8*)&Ss[m * 128 + ch * 8];
        }
        #pragma unroll
        for (int jj = 0; jj < 2; ++jj) {
            int c = wn * 32 + jj * 16 + l16;   // class index 0..63
            b2[jj] = *(const bf16x8*)&Wctx_t[(size_t)c * POOL + n0 + kb * 32 + quad * 8];
        }
        #pragma unroll
        for (int i = 0; i < 4; ++i)
            #pragma unroll
            for (int jj = 0; jj < 2; ++jj)
                acc2[i][jj] = __builtin_amdgcn_mfma_f32_16x16x32_bf16(a2[i], b2[jj], acc2[i][jj], 0, 0, 0);
    }
    #pragma unroll
    for (int i = 0; i < 4; ++i) {
        int rbase = m0 + wm * 64 + i * 16 + quad * 4;
        #pragma unroll
        for (int jj = 0; jj < 2; ++jj) {
            int c = wn * 32 + jj * 16 + l16;
            if (c < NRC) {
                #pragma unroll
                for (int rr = 0; rr < 4; ++rr)
                    atomicAdd(&out[(size_t)(rbase + rr) * NRC + c], acc2[i][jj][rr]);
            }
        }
    }
}

// ---------------- launcher ----------------

extern "C" void kernel_launch(void* const* d_in, const int* in_sizes, int n_in,
                              void* d_out, int out_size, void* d_ws, size_t ws_size,
                              hipStream_t stream) {
    const float* edge_ctx = (const float*)d_in[0];
    const float* uni      = (const float*)d_in[1];
    const int*   rel      = (const int*)d_in[2];
    const int*   obj      = (const int*)d_in[3];
    const float* W_emb    = (const float*)d_in[4];
    const float* b_emb    = (const float*)d_in[5];
    const float* W_cat    = (const float*)d_in[6];
    const float* b_cat    = (const float*)d_in[7];
    const float* W_ctx    = (const float*)d_in[8];
    const float* b_ctx    = (const float*)d_in[9];
    const float* freq     = (const float*)d_in[10];
    float* out = (float*)d_out;

    char* p = (char*)d_ws;
    bf16_t* C1     = (bf16_t*)p; p += (size_t)N_OBJ * 1024 * 2;
    bf16_t* ecb    = (bf16_t*)p; p += (size_t)N_OBJ * HID * 2;
    bf16_t* Wemb_t = (bf16_t*)p; p += (size_t)1024 * HID * 2;
    bf16_t* Wcat_t = (bf16_t*)p; p += (size_t)POOL * 1024 * 2;
    bf16_t* Wctx_t = (bf16_t*)p; p += (size_t)64 * POOL * 2;

    convert_bf16_kernel<<<2048, 256, 0, stream>>>(edge_ctx, ecb, N_OBJ * HID / 4);
    transpose_bf16_kernel<<<dim3(1024 / 32, HID / 32), dim3(32, 8), 0, stream>>>(W_emb, Wemb_t, HID, 1024, 1024);
    transpose_bf16_kernel<<<dim3(POOL / 32, 1024 / 32), dim3(32, 8), 0, stream>>>(W_cat, Wcat_t, 1024, POOL, POOL);
    transpose_bf16_kernel<<<dim3(2, POOL / 32), dim3(32, 8), 0, stream>>>(W_ctx, Wctx_t, POOL, NRC, 64);
    init_out_kernel<<<N_REL / 4, 256, 0, stream>>>(rel, obj, b_ctx, freq, out);

    gemm1_kernel<<<dim3(N_OBJ / 128, 1024 / 128), 256, 0, stream>>>(ecb, Wemb_t, b_emb, C1);
    gemm2_fused_kernel<<<dim3(N_REL / 128, POOL / 128), 256, 0, stream>>>(C1, Wcat_t, Wctx_t, rel, b_cat, uni, out);
}